// Round 14
// baseline (1376.491 us; speedup 1.0000x reference)
//
#include <hip/hip_runtime.h>
#include <hip/hip_bf16.h>
#include <cstdio>
#include <cstdint>

#define BB   4
#define SS   2048
#define DIMM 2048
#define HH   16
#define NOPED 128
#define QKD  192
#define KVR  512
#define DQK  576
#define SCALE_F 0.07216878364870323f  // 192^-0.5

typedef __attribute__((ext_vector_type(4))) float f32x4;
typedef __attribute__((ext_vector_type(8))) __bf16 bf16x8;
typedef __attribute__((ext_vector_type(8))) unsigned short u16x8;

__device__ __forceinline__ f32x4 mfma16(bf16x8 a, bf16x8 b, f32x4 c) {
  return __builtin_amdgcn_mfma_f32_16x16x32_bf16(a, b, c, 0, 0, 0);
}

// async global->LDS, 16B per lane; LDS dest must be wave-uniform base + lane*16
__device__ __forceinline__ void gl16(const __bf16* g, __bf16* l) {
  __builtin_amdgcn_global_load_lds(
      (const __attribute__((address_space(1))) unsigned int*)g,
      (__attribute__((address_space(3))) unsigned int*)l, 16, 0, 0);
}

// ---------------- f32 -> bf16 convert ----------------
__global__ void k_cvt(const float* __restrict__ in, __bf16* __restrict__ out, int n) {
  int i = (blockIdx.x * 256 + threadIdx.x) * 8;
  if (i >= n) return;
  float4 a = *(const float4*)(in + i);
  float4 b = *(const float4*)(in + i + 4);
  bf16x8 v;
  v[0] = (__bf16)a.x; v[1] = (__bf16)a.y; v[2] = (__bf16)a.z; v[3] = (__bf16)a.w;
  v[4] = (__bf16)b.x; v[5] = (__bf16)b.y; v[6] = (__bf16)b.z; v[7] = (__bf16)b.w;
  *(bf16x8*)(out + i) = v;
}

// ---------------- f32 transpose -> bf16 (batched) ----------------
__global__ void k_tr(const float* __restrict__ in, __bf16* __restrict__ out,
                     int R, int C, int64_t inBS, int64_t outBS) {
  in  += (int64_t)blockIdx.z * inBS;
  out += (int64_t)blockIdx.z * outBS;
  __shared__ float t[32][33];
  int c0 = blockIdx.x * 32, r0 = blockIdx.y * 32;
#pragma unroll
  for (int i = 0; i < 4; i++) {
    int r = r0 + threadIdx.y + i * 8, c = c0 + threadIdx.x;
    if (r < R && c < C) t[threadIdx.y + i * 8][threadIdx.x] = in[(int64_t)r * C + c];
  }
  __syncthreads();
#pragma unroll
  for (int i = 0; i < 4; i++) {
    int c = c0 + threadIdx.y + i * 8, r = r0 + threadIdx.x;
    if (c < C && r < R) out[(int64_t)c * R + r] = (__bf16)t[threadIdx.x][threadIdx.y + i * 8];
  }
}

// ---------------- generic batched MFMA GEMM: C = scale * A(M,K) x Bt(N,K)^T ----------------
template <bool OUTF32>
__global__ __launch_bounds__(256) void k_gemm(
    const __bf16* __restrict__ A, const __bf16* __restrict__ Bt, void* __restrict__ Cv,
    int N, int K, int lda, int ldb, int ldc,
    int64_t aSB, int64_t aSH, int64_t bSH, int64_t cSB, int64_t cSH, int Hdiv, float scale) {
  const int z = blockIdx.z;
  const int zb = z / Hdiv, zh = z % Hdiv;
  const int64_t aBase = zb * aSB + zh * aSH;
  const int64_t bBase = zh * bSH;
  const int64_t cBase = zb * cSB + zh * cSH;
  const int n0 = blockIdx.x * 128, m0 = blockIdx.y * 128;
  const int tid = threadIdx.x, lane = tid & 63, wid = tid >> 6;
  const int p = lane & 15, g = lane >> 4;
  const int wr = (wid >> 1) * 64, wc = (wid & 1) * 64;
  __shared__ alignas(16) __bf16 lA[128 * 32];
  __shared__ alignas(16) __bf16 lB[128 * 32];
  const f32x4 fz = {};
  f32x4 acc[4][4];
#pragma unroll
  for (int i = 0; i < 4; i++)
#pragma unroll
    for (int j = 0; j < 4; j++) acc[i][j] = fz;
  const __bf16* gA0 = A + aBase + (int64_t)(m0 + (tid >> 2)) * lda + (tid & 3) * 8;
  const __bf16* gA1 = A + aBase + (int64_t)(m0 + 64 + (tid >> 2)) * lda + (tid & 3) * 8;
  const __bf16* gB0 = Bt + bBase + (int64_t)(n0 + (tid >> 2)) * ldb + (tid & 3) * 8;
  const __bf16* gB1 = Bt + bBase + (int64_t)(n0 + 64 + (tid >> 2)) * ldb + (tid & 3) * 8;
  auto stage = [&](int kt) {
    gl16(gA0 + kt, &lA[tid * 8]);
    gl16(gA1 + kt, &lA[(256 + tid) * 8]);
    gl16(gB0 + kt, &lB[tid * 8]);
    gl16(gB1 + kt, &lB[(256 + tid) * 8]);
  };
  stage(0);
  for (int kt = 0; kt < K; kt += 32) {
    asm volatile("s_waitcnt vmcnt(0)" ::: "memory");
    __builtin_amdgcn_s_barrier();
    bf16x8 af[4], bfr[4];
#pragma unroll
    for (int mi = 0; mi < 4; mi++) af[mi]  = *(const bf16x8*)&lA[(wr + mi * 16 + p) * 32 + g * 8];
#pragma unroll
    for (int ni = 0; ni < 4; ni++) bfr[ni] = *(const bf16x8*)&lB[(wc + ni * 16 + p) * 32 + g * 8];
#pragma unroll
    for (int mi = 0; mi < 4; mi++)
#pragma unroll
      for (int ni = 0; ni < 4; ni++) acc[mi][ni] = mfma16(af[mi], bfr[ni], acc[mi][ni]);
    asm volatile("s_waitcnt lgkmcnt(0)" ::: "memory");
    __builtin_amdgcn_s_barrier();
    if (kt + 32 < K) stage(kt + 32);
  }
#pragma unroll
  for (int mi = 0; mi < 4; mi++) {
#pragma unroll
    for (int ni = 0; ni < 4; ni++) {
      const int n = n0 + wc + ni * 16 + p;
      if (n < N) {
#pragma unroll
        for (int r = 0; r < 4; r++) {
          const int m = m0 + wr + mi * 16 + g * 4 + r;
          float v = acc[mi][ni][r] * scale;
          if (OUTF32) ((float*)Cv)[cBase + (int64_t)m * ldc + n] = v;
          else        ((__bf16*)Cv)[cBase + (int64_t)m * ldc + n] = (__bf16)v;
        }
      }
    }
  }
}

// ---------------- kv prep: rms-norm -> Kcat[:,:512]; rope -> Kcat[:,512:576] ----------------
__global__ __launch_bounds__(64) void k_kvprep(
    const __bf16* __restrict__ kvfull, const float* __restrict__ wnorm,
    const float* __restrict__ fc, const float* __restrict__ fs,
    __bf16* __restrict__ Kcat) {
  const int row = blockIdx.x;
  const int lane = threadIdx.x;
  const int s = row & 2047;
  const __bf16* src = kvfull + (int64_t)row * DQK;
  bf16x8 v = *(const bf16x8*)(src + lane * 8);
  float f[8], ss = 0.f;
#pragma unroll
  for (int j = 0; j < 8; j++) { f[j] = (float)v[j]; ss += f[j] * f[j]; }
#pragma unroll
  for (int mk = 1; mk < 64; mk <<= 1) ss += __shfl_xor(ss, mk, 64);
  float rn = rsqrtf(ss * (1.f / 512.f) + 1e-6f);
  bf16x8 o;
#pragma unroll
  for (int j = 0; j < 8; j++) o[j] = (__bf16)(f[j] * rn * wnorm[lane * 8 + j]);
  *(bf16x8*)(Kcat + (int64_t)row * DQK + lane * 8) = o;
  if (lane < 32) {
    float xr = (float)src[512 + 2 * lane];
    float xi = (float)src[512 + 2 * lane + 1];
    float c = fc[s * 32 + lane], sn = fs[s * 32 + lane];
    Kcat[(int64_t)row * DQK + 512 + 2 * lane]     = (__bf16)(xr * c - xi * sn);
    Kcat[(int64_t)row * DQK + 512 + 2 * lane + 1] = (__bf16)(xr * sn + xi * c);
  }
}

// ---------------- q rope ----------------
__global__ void k_qpe(const __bf16* __restrict__ qfull, const float* __restrict__ fc,
                      const float* __restrict__ fs, __bf16* __restrict__ Qcat) {
  int idx = blockIdx.x * 256 + threadIdx.x;
  if (idx >= BB * HH * SS * 32) return;
  int i = idx & 31, s = (idx >> 5) & 2047, h = (idx >> 16) & 15, b = idx >> 20;
  const __bf16* src = qfull + ((int64_t)(b * SS + s)) * 3072 + h * QKD + NOPED;
  float xr = (float)src[2 * i], xi = (float)src[2 * i + 1];
  float c = fc[s * 32 + i], sn = fs[s * 32 + i];
  __bf16* dst = Qcat + (((int64_t)(b * HH + h)) * SS + s) * DQK + 512;
  dst[2 * i]     = (__bf16)((xr * c - xi * sn) * SCALE_F);
  dst[2 * i + 1] = (__bf16)((xr * sn + xi * c) * SCALE_F);
}

// ---------------- flash attention v14 = v13 + __launch_bounds__(256, 3) ----------------
// v13 measured: VGPR_Count 116 arch but the UNIFIED VGPR+AGPR allocation is
// ~220/wave (qreg 72 + acc 32 + sc/softmax/addressing) -> register file caps
// residency at 2 waves/SIMD even though LDS (49 KB x 3) allows 3 blocks/CU.
// v14: (256,3) caps total alloc at 170/wave; the minimum live set (~165) just
// fits via rematerialized addressing -> 3 waves/SIMD, 3 blocks/CU. FETCH is
// the spill sentinel (>500 MB -> revert to (256,2)). Math byte-identical.
__global__ __launch_bounds__(256, 3) void k_attn(
    const __bf16* __restrict__ Qcat, const __bf16* __restrict__ Kcat,
    const __bf16* __restrict__ Vt2, __bf16* __restrict__ Ohead) {
  const int gx = blockIdx.x;            // XCD selector
  const int w  = blockIdx.y;
  const int z  = gx * 8 + (w & 7);      // (b,h): b = z>>4
  const int yv = w >> 3;                // depth slot 0..31
  const int kk = yv >> 2, cc = yv & 3;
  const int bx = (kk & 1) ? (31 - ((kk - 1) << 1) - cc) : ((kk << 1) + cc);
  const int b = z >> 4, h = z & 15;
  const int q0 = bx * 64;
  const int tid = threadIdx.x, lane = tid & 63, wid = tid >> 6;
  const int p = lane & 15, g = lane >> 4;
  const int qw = q0 + wid * 16;
  __shared__ alignas(16) __bf16 lK[32 * 576];   // 36864 B
  __shared__ alignas(16) __bf16 lV[128 * 32];   //  8192 B
  __shared__ alignas(16) __bf16 lP[4 * 512];    //  4096 B  (total 49152)

  // ---- Q hoist ----
  bf16x8 qreg[18];
  {
    const __bf16* qb = Qcat + ((int64_t)z * SS + qw + p) * DQK + g * 8;
#pragma unroll
    for (int kc = 0; kc < 18; kc++) qreg[kc] = *(const bf16x8*)(qb + kc * 32);
  }
  bf16x8 ones;
#pragma unroll
  for (int j = 0; j < 8; j++) ones[j] = (__bf16)1.0f;
  const f32x4 fz = {};
  f32x4 acc[8];                                  // 16 q-rows x 128 d
#pragma unroll
  for (int ct = 0; ct < 8; ct++) acc[ct] = fz;
  float mrun[4] = {-1e30f, -1e30f, -1e30f, -1e30f};
  float lrun[4] = {0.f, 0.f, 0.f, 0.f};

  const __bf16* kBase = Kcat + (int64_t)b * SS * DQK;
  const __bf16* vBase = Vt2 + (int64_t)z * 128 * SS;

  auto stage = [&](int t0) {
    const __bf16* kb = kBase + (int64_t)t0 * DQK;
#pragma unroll
    for (int it = 0; it < 9; it++) {
      int slot = it * 256 + tid;
      int row = slot / 72, u = slot - row * 72;
      gl16(kb + row * DQK + ((u ^ (row & 7)) * 8), &lK[(it * 256 + tid) * 8]);
    }
    const __bf16* vb = vBase + t0;
#pragma unroll
    for (int it = 0; it < 2; it++) {
      int slot = it * 256 + tid;
      int c = slot >> 2, u = slot & 3;
      gl16(vb + c * SS + ((u ^ ((c >> 1) & 3)) * 8), &lV[(it * 256 + tid) * 8]);
    }
  };

  const int nsteps = bx * 2 + 2;
  stage(0);
  const int vkey = (p >> 1) & 3;
  for (int st = 0; st < nsteps; st++) {
    const int t0 = st * 32;
    asm volatile("s_waitcnt vmcnt(0)" ::: "memory");
    __builtin_amdgcn_s_barrier();   // tile resident in lK/lV

    // ---- QK^T (2 interleaved partial accumulators) ----
    __builtin_amdgcn_s_setprio(1);
    f32x4 sca[2], scb[2];
    sca[0] = fz; sca[1] = fz; scb[0] = fz; scb[1] = fz;
#pragma unroll
    for (int kc = 0; kc < 18; kc += 2) {
#pragma unroll
      for (int n = 0; n < 2; n++) {
        int trow = n * 16 + p;
        bf16x8 bf0 = *(const bf16x8*)&lK[trow * 576 + (((4 * kc + g) ^ (trow & 7))) * 8];
        bf16x8 bf1 = *(const bf16x8*)&lK[trow * 576 + (((4 * (kc + 1) + g) ^ (trow & 7))) * 8];
        sca[n] = mfma16(qreg[kc], bf0, sca[n]);
        scb[n] = mfma16(qreg[kc + 1], bf1, scb[n]);
      }
    }
    __builtin_amdgcn_s_setprio(0);
    f32x4 sc[2];
#pragma unroll
    for (int n = 0; n < 2; n++)
#pragma unroll
      for (int r = 0; r < 4; r++) sc[n][r] = sca[n][r] + scb[n][r];
    if (t0 + 31 > qw) {
#pragma unroll
      for (int n = 0; n < 2; n++) {
        int t = t0 + n * 16 + p;
#pragma unroll
        for (int r = 0; r < 4; r++) {
          int q = qw + g * 4 + r;
          if (t > q) sc[n][r] = -1e9f;
        }
      }
    }

    // ---- softmax max + P store (defer-max T13, THR=8); row-sum via MFMA ----
    float es[4];
    int needAny = 0;
#pragma unroll
    for (int r = 0; r < 4; r++) {
      float mx = fmaxf(sc[0][r], sc[1][r]);
#pragma unroll
      for (int mk = 1; mk < 16; mk <<= 1) mx = fmaxf(mx, __shfl_xor(mx, mk, 64));
      if (mx > mrun[r] + 8.f) { es[r] = __expf(mrun[r] - mx); mrun[r] = mx; needAny = 1; }
      else es[r] = 1.f;
      float s0 = __expf(sc[0][r] - mrun[r]);
      float s1 = __expf(sc[1][r] - mrun[r]);
      int prow = g * 4 + r;
      int swz = ((prow >> 1) & 3) * 8;
      lP[wid * 512 + prow * 32 + (p ^ swz)]        = (__bf16)s0;
      lP[wid * 512 + prow * 32 + ((16 + p) ^ swz)] = (__bf16)s1;
    }
    if (__any(needAny)) {
#pragma unroll
      for (int ct = 0; ct < 8; ct++)
#pragma unroll
        for (int r = 0; r < 4; r++) acc[ct][r] *= es[r];
    }
    bf16x8 pa = *(const bf16x8*)&lP[wid * 512 + p * 32 + ((g ^ vkey) * 8)];
    {
      f32x4 rs = mfma16(pa, ones, fz);   // row-sums of own P tile
#pragma unroll
      for (int r = 0; r < 4; r++) lrun[r] = lrun[r] * es[r] + rs[r];
    }

    // ---- PV: 16 q-rows x 128 d ----
    __builtin_amdgcn_s_setprio(1);
#pragma unroll
    for (int ct = 0; ct < 8; ct++) {
      int c = ct * 16 + p;
      bf16x8 bv = *(const bf16x8*)&lV[c * 32 + ((g ^ vkey) * 8)];
      acc[ct] = mfma16(pa, bv, acc[ct]);
    }
    __builtin_amdgcn_s_setprio(0);
    asm volatile("s_waitcnt lgkmcnt(0)" ::: "memory");
    __builtin_amdgcn_s_barrier();   // everyone done reading lK/lV
    if (st + 1 < nsteps) stage(t0 + 32);
  }

  // ---- epilogue: normalize + store to o_head[b][s][h*128+d] ----
#pragma unroll
  for (int r = 0; r < 4; r++) {
    float inv = 1.f / lrun[r];
    int64_t rb = ((int64_t)b * SS + qw + g * 4 + r) * 2048 + h * 128;
#pragma unroll
    for (int ct = 0; ct < 8; ct++) Ohead[rb + ct * 16 + p] = (__bf16)(acc[ct][r] * inv);
  }
}

extern "C" void kernel_launch(void* const* d_in, const int* in_sizes, int n_in,
                              void* d_out, int out_size, void* d_ws, size_t ws_size,
                              hipStream_t stream) {
  const float* x     = (const float*)d_in[0];
  const float* wq    = (const float*)d_in[1];
  const float* wkv_a = (const float*)d_in[2];
  const float* kvw   = (const float*)d_in[3];
  const float* wkv_b = (const float*)d_in[4];
  const float* wo    = (const float*)d_in[5];
  const float* fc    = (const float*)d_in[6];
  const float* fs    = (const float*)d_in[7];
  float* out = (float*)d_out;

  char* base = (char*)d_ws;
  const size_t OFF_KCAT  = 0;
  const size_t OFF_VT    = OFF_KCAT + 9437184ull;   // (old Vt slot; unused)
  const size_t OFF_WKVB  = OFF_VT + 8388608ull;
  const size_t OFF_WOT   = OFF_WKVB + 4194304ull;
  const size_t OFF_QCAT  = OFF_WOT + 8388608ull;
  const size_t OFF_OHEAD = OFF_QCAT + 150994944ull;
  const size_t OFF_QFULL = OFF_OHEAD + 33554432ull;
  const size_t TOTAL     = OFF_QFULL + 50331648ull;

  __bf16* Kcat    = (__bf16*)(base + OFF_KCAT);
  __bf16* wkvb_bf = (__bf16*)(base + OFF_WKVB);
  __bf16* woT     = (__bf16*)(base + OFF_WOT);
  __bf16* Qcat    = (__bf16*)(base + OFF_QCAT);
  __bf16* o_head  = (__bf16*)(base + OFF_OHEAD);
  __bf16* qfull   = (__bf16*)(base + OFF_QFULL);
  __bf16* Vt2     = (__bf16*)(base + OFF_QFULL);          // aliases qfull (dead after qpe)
  __bf16* wqT    = (__bf16*)(base + OFF_KCAT);            // dead before kvprep
  __bf16* wkvaT  = (__bf16*)(base + OFF_KCAT + 12582912); // dead before kvprep
  __bf16* xb     = (__bf16*)(base + OFF_QCAT);            // dead before q_abs
  __bf16* kvfull = (__bf16*)(base + OFF_QCAT + 33554432); // dead before q_abs
  __bf16* wbTn   = (__bf16*)(base + OFF_OHEAD);           // dead before attn

  if (ws_size < TOTAL) {
    fprintf(stderr, "kernel_launch: ws too small: need %zu have %zu\n", TOTAL, ws_size);
    return;
  }

  k_cvt<<<8192, 256, 0, stream>>>(x, xb, BB * SS * DIMM);
  k_cvt<<<1024, 256, 0, stream>>>(wkv_b, wkvb_bf, 4096 * 512);
  k_tr<<<dim3(96, 64, 1), dim3(32, 8), 0, stream>>>(wq, wqT, 2048, 3072, 0, 0);
  k_tr<<<dim3(18, 64, 1), dim3(32, 8), 0, stream>>>(wkv_a, wkvaT, 2048, 576, 0, 0);
  k_tr<<<dim3(64, 64, 1), dim3(32, 8), 0, stream>>>(wo, woT, 2048, 2048, 0, 0);
  k_tr<<<dim3(16, 4, 16), dim3(32, 8), 0, stream>>>(wkv_b, wbTn, 128, 512,
                                                    (int64_t)256 * 512, (int64_t)512 * 128);
  // qfull = xb @ wq
  k_gemm<false><<<dim3(24, 64, 1), 256, 0, stream>>>(
      xb, wqT, qfull, 3072, 2048, 2048, 2048, 3072, 0, 0, 0, 0, 0, 1, 1.0f);
  // kvfull = xb @ wkv_a
  k_gemm<false><<<dim3(5, 64, 1), 256, 0, stream>>>(
      xb, wkvaT, kvfull, 576, 2048, 2048, 2048, 576, 0, 0, 0, 0, 0, 1, 1.0f);
  k_kvprep<<<8192, 64, 0, stream>>>(kvfull, kvw, fc, fs, Kcat);
  // q_abs (batched over b,h) -> Qcat[:, :512], scaled
  k_gemm<false><<<dim3(4, 16, 64), 256, 0, stream>>>(
      qfull, wbTn, Qcat, 512, 128, 3072, 128, 576,
      (int64_t)SS * 3072, (int64_t)QKD, (int64_t)512 * 128,
      (int64_t)HH * SS * DQK, (int64_t)SS * DQK, 16, SCALE_F);
  k_qpe<<<16384, 256, 0, stream>>>(qfull, fc, fs, Qcat);
  // V_head[z][d=128][t] = w_b2[h] @ kv_c^T  (z decoded as zb=h, zh=b via Hdiv=4)
  k_gemm<false><<<dim3(16, 1, 64), 256, 0, stream>>>(
      wkvb_bf + 128 * 512, Kcat, Vt2, 2048, 512, 512, DQK, 2048,
      (int64_t)256 * 512, 0, (int64_t)SS * DQK,
      (int64_t)128 * 2048, (int64_t)16 * 128 * 2048, 4, 1.0f);
  // attention: grid (8=xcd, 256=w) -> o_head[b][s][h*128+d]
  k_attn<<<dim3(8, 256), 256, 0, stream>>>(Qcat, Kcat, Vt2, o_head);
  // out = o_head @ wo
  k_gemm<true><<<dim3(16, 64, 1), 256, 0, stream>>>(
      o_head, woT, out, 2048, 2048, 2048, 2048, 2048, 0, 0, 0, 0, 0, 1, 1.0f);
}

// Round 15
// 771.826 us; speedup vs baseline: 1.7834x; 1.7834x over previous
//
#include <hip/hip_runtime.h>
#include <hip/hip_bf16.h>
#include <cstdio>
#include <cstdint>

#define BB   4
#define SS   2048
#define DIMM 2048
#define HH   16
#define NOPED 128
#define QKD  192
#define KVR  512
#define DQK  576
#define SCALE_F 0.07216878364870323f  // 192^-0.5

typedef __attribute__((ext_vector_type(4))) float f32x4;
typedef __attribute__((ext_vector_type(8))) __bf16 bf16x8;
typedef __attribute__((ext_vector_type(8))) unsigned short u16x8;

__device__ __forceinline__ f32x4 mfma16(bf16x8 a, bf16x8 b, f32x4 c) {
  return __builtin_amdgcn_mfma_f32_16x16x32_bf16(a, b, c, 0, 0, 0);
}

// async global->LDS, 16B per lane; LDS dest must be wave-uniform base + lane*16
__device__ __forceinline__ void gl16(const __bf16* g, __bf16* l) {
  __builtin_amdgcn_global_load_lds(
      (const __attribute__((address_space(1))) unsigned int*)g,
      (__attribute__((address_space(3))) unsigned int*)l, 16, 0, 0);
}

// ---------------- f32 -> bf16 convert ----------------
__global__ void k_cvt(const float* __restrict__ in, __bf16* __restrict__ out, int n) {
  int i = (blockIdx.x * 256 + threadIdx.x) * 8;
  if (i >= n) return;
  float4 a = *(const float4*)(in + i);
  float4 b = *(const float4*)(in + i + 4);
  bf16x8 v;
  v[0] = (__bf16)a.x; v[1] = (__bf16)a.y; v[2] = (__bf16)a.z; v[3] = (__bf16)a.w;
  v[4] = (__bf16)b.x; v[5] = (__bf16)b.y; v[6] = (__bf16)b.z; v[7] = (__bf16)b.w;
  *(bf16x8*)(out + i) = v;
}

// ---------------- f32 transpose -> bf16 (batched) ----------------
__global__ void k_tr(const float* __restrict__ in, __bf16* __restrict__ out,
                     int R, int C, int64_t inBS, int64_t outBS) {
  in  += (int64_t)blockIdx.z * inBS;
  out += (int64_t)blockIdx.z * outBS;
  __shared__ float t[32][33];
  int c0 = blockIdx.x * 32, r0 = blockIdx.y * 32;
#pragma unroll
  for (int i = 0; i < 4; i++) {
    int r = r0 + threadIdx.y + i * 8, c = c0 + threadIdx.x;
    if (r < R && c < C) t[threadIdx.y + i * 8][threadIdx.x] = in[(int64_t)r * C + c];
  }
  __syncthreads();
#pragma unroll
  for (int i = 0; i < 4; i++) {
    int c = c0 + threadIdx.y + i * 8, r = r0 + threadIdx.x;
    if (c < C && r < R) out[(int64_t)c * R + r] = (__bf16)t[threadIdx.x][threadIdx.y + i * 8];
  }
}

// ---------------- generic batched MFMA GEMM: C = scale * A(M,K) x Bt(N,K)^T ----------------
template <bool OUTF32>
__global__ __launch_bounds__(256) void k_gemm(
    const __bf16* __restrict__ A, const __bf16* __restrict__ Bt, void* __restrict__ Cv,
    int N, int K, int lda, int ldb, int ldc,
    int64_t aSB, int64_t aSH, int64_t bSH, int64_t cSB, int64_t cSH, int Hdiv, float scale) {
  const int z = blockIdx.z;
  const int zb = z / Hdiv, zh = z % Hdiv;
  const int64_t aBase = zb * aSB + zh * aSH;
  const int64_t bBase = zh * bSH;
  const int64_t cBase = zb * cSB + zh * cSH;
  const int n0 = blockIdx.x * 128, m0 = blockIdx.y * 128;
  const int tid = threadIdx.x, lane = tid & 63, wid = tid >> 6;
  const int p = lane & 15, g = lane >> 4;
  const int wr = (wid >> 1) * 64, wc = (wid & 1) * 64;
  __shared__ alignas(16) __bf16 lA[128 * 32];
  __shared__ alignas(16) __bf16 lB[128 * 32];
  const f32x4 fz = {};
  f32x4 acc[4][4];
#pragma unroll
  for (int i = 0; i < 4; i++)
#pragma unroll
    for (int j = 0; j < 4; j++) acc[i][j] = fz;
  const __bf16* gA0 = A + aBase + (int64_t)(m0 + (tid >> 2)) * lda + (tid & 3) * 8;
  const __bf16* gA1 = A + aBase + (int64_t)(m0 + 64 + (tid >> 2)) * lda + (tid & 3) * 8;
  const __bf16* gB0 = Bt + bBase + (int64_t)(n0 + (tid >> 2)) * ldb + (tid & 3) * 8;
  const __bf16* gB1 = Bt + bBase + (int64_t)(n0 + 64 + (tid >> 2)) * ldb + (tid & 3) * 8;
  auto stage = [&](int kt) {
    gl16(gA0 + kt, &lA[tid * 8]);
    gl16(gA1 + kt, &lA[(256 + tid) * 8]);
    gl16(gB0 + kt, &lB[tid * 8]);
    gl16(gB1 + kt, &lB[(256 + tid) * 8]);
  };
  stage(0);
  for (int kt = 0; kt < K; kt += 32) {
    asm volatile("s_waitcnt vmcnt(0)" ::: "memory");
    __builtin_amdgcn_s_barrier();
    bf16x8 af[4], bfr[4];
#pragma unroll
    for (int mi = 0; mi < 4; mi++) af[mi]  = *(const bf16x8*)&lA[(wr + mi * 16 + p) * 32 + g * 8];
#pragma unroll
    for (int ni = 0; ni < 4; ni++) bfr[ni] = *(const bf16x8*)&lB[(wc + ni * 16 + p) * 32 + g * 8];
#pragma unroll
    for (int mi = 0; mi < 4; mi++)
#pragma unroll
      for (int ni = 0; ni < 4; ni++) acc[mi][ni] = mfma16(af[mi], bfr[ni], acc[mi][ni]);
    asm volatile("s_waitcnt lgkmcnt(0)" ::: "memory");
    __builtin_amdgcn_s_barrier();
    if (kt + 32 < K) stage(kt + 32);
  }
#pragma unroll
  for (int mi = 0; mi < 4; mi++) {
#pragma unroll
    for (int ni = 0; ni < 4; ni++) {
      const int n = n0 + wc + ni * 16 + p;
      if (n < N) {
#pragma unroll
        for (int r = 0; r < 4; r++) {
          const int m = m0 + wr + mi * 16 + g * 4 + r;
          float v = acc[mi][ni][r] * scale;
          if (OUTF32) ((float*)Cv)[cBase + (int64_t)m * ldc + n] = v;
          else        ((__bf16*)Cv)[cBase + (int64_t)m * ldc + n] = (__bf16)v;
        }
      }
    }
  }
}

// ---------------- kv prep: rms-norm -> Kcat[:,:512]; rope -> Kcat[:,512:576] ----------------
__global__ __launch_bounds__(64) void k_kvprep(
    const __bf16* __restrict__ kvfull, const float* __restrict__ wnorm,
    const float* __restrict__ fc, const float* __restrict__ fs,
    __bf16* __restrict__ Kcat) {
  const int row = blockIdx.x;
  const int lane = threadIdx.x;
  const int s = row & 2047;
  const __bf16* src = kvfull + (int64_t)row * DQK;
  bf16x8 v = *(const bf16x8*)(src + lane * 8);
  float f[8], ss = 0.f;
#pragma unroll
  for (int j = 0; j < 8; j++) { f[j] = (float)v[j]; ss += f[j] * f[j]; }
#pragma unroll
  for (int mk = 1; mk < 64; mk <<= 1) ss += __shfl_xor(ss, mk, 64);
  float rn = rsqrtf(ss * (1.f / 512.f) + 1e-6f);
  bf16x8 o;
#pragma unroll
  for (int j = 0; j < 8; j++) o[j] = (__bf16)(f[j] * rn * wnorm[lane * 8 + j]);
  *(bf16x8*)(Kcat + (int64_t)row * DQK + lane * 8) = o;
  if (lane < 32) {
    float xr = (float)src[512 + 2 * lane];
    float xi = (float)src[512 + 2 * lane + 1];
    float c = fc[s * 32 + lane], sn = fs[s * 32 + lane];
    Kcat[(int64_t)row * DQK + 512 + 2 * lane]     = (__bf16)(xr * c - xi * sn);
    Kcat[(int64_t)row * DQK + 512 + 2 * lane + 1] = (__bf16)(xr * sn + xi * c);
  }
}

// ---------------- q rope ----------------
__global__ void k_qpe(const __bf16* __restrict__ qfull, const float* __restrict__ fc,
                      const float* __restrict__ fs, __bf16* __restrict__ Qcat) {
  int idx = blockIdx.x * 256 + threadIdx.x;
  if (idx >= BB * HH * SS * 32) return;
  int i = idx & 31, s = (idx >> 5) & 2047, h = (idx >> 16) & 15, b = idx >> 20;
  const __bf16* src = qfull + ((int64_t)(b * SS + s)) * 3072 + h * QKD + NOPED;
  float xr = (float)src[2 * i], xi = (float)src[2 * i + 1];
  float c = fc[s * 32 + i], sn = fs[s * 32 + i];
  __bf16* dst = Qcat + (((int64_t)(b * HH + h)) * SS + s) * DQK + 512;
  dst[2 * i]     = (__bf16)((xr * c - xi * sn) * SCALE_F);
  dst[2 * i + 1] = (__bf16)((xr * sn + xi * c) * SCALE_F);
}

// ---------------- flash attention v15 = v13 exactly (256,2) ----------------
// v14's (256,3) spilled (FETCH 153 MB -> 2.08 GB): the true minimum live set
// is ~220 regs -> 2 waves/SIMD is the hard residency ceiling. v13 measured at
// ~97% of its geometry's LDS-BW floor (225 KB/block-step @ 256 B/cy = 880 cy
// vs 904 cy measured), so this configuration is the closed optimum for the
// 16-q-rows-per-wave fragment geometry.
__global__ __launch_bounds__(256, 2) void k_attn(
    const __bf16* __restrict__ Qcat, const __bf16* __restrict__ Kcat,
    const __bf16* __restrict__ Vt2, __bf16* __restrict__ Ohead) {
  const int gx = blockIdx.x;            // XCD selector
  const int w  = blockIdx.y;
  const int z  = gx * 8 + (w & 7);      // (b,h): b = z>>4
  const int yv = w >> 3;                // depth slot 0..31
  const int kk = yv >> 2, cc = yv & 3;
  const int bx = (kk & 1) ? (31 - ((kk - 1) << 1) - cc) : ((kk << 1) + cc);
  const int b = z >> 4, h = z & 15;
  const int q0 = bx * 64;
  const int tid = threadIdx.x, lane = tid & 63, wid = tid >> 6;
  const int p = lane & 15, g = lane >> 4;
  const int qw = q0 + wid * 16;
  __shared__ alignas(16) __bf16 lK[32 * 576];   // 36864 B
  __shared__ alignas(16) __bf16 lV[128 * 32];   //  8192 B
  __shared__ alignas(16) __bf16 lP[4 * 512];    //  4096 B  (total 49152)

  // ---- Q hoist ----
  bf16x8 qreg[18];
  {
    const __bf16* qb = Qcat + ((int64_t)z * SS + qw + p) * DQK + g * 8;
#pragma unroll
    for (int kc = 0; kc < 18; kc++) qreg[kc] = *(const bf16x8*)(qb + kc * 32);
  }
  bf16x8 ones;
#pragma unroll
  for (int j = 0; j < 8; j++) ones[j] = (__bf16)1.0f;
  const f32x4 fz = {};
  f32x4 acc[8];                                  // 16 q-rows x 128 d
#pragma unroll
  for (int ct = 0; ct < 8; ct++) acc[ct] = fz;
  float mrun[4] = {-1e30f, -1e30f, -1e30f, -1e30f};
  float lrun[4] = {0.f, 0.f, 0.f, 0.f};

  const __bf16* kBase = Kcat + (int64_t)b * SS * DQK;
  const __bf16* vBase = Vt2 + (int64_t)z * 128 * SS;

  auto stage = [&](int t0) {
    const __bf16* kb = kBase + (int64_t)t0 * DQK;
#pragma unroll
    for (int it = 0; it < 9; it++) {
      int slot = it * 256 + tid;
      int row = slot / 72, u = slot - row * 72;
      gl16(kb + row * DQK + ((u ^ (row & 7)) * 8), &lK[(it * 256 + tid) * 8]);
    }
    const __bf16* vb = vBase + t0;
#pragma unroll
    for (int it = 0; it < 2; it++) {
      int slot = it * 256 + tid;
      int c = slot >> 2, u = slot & 3;
      gl16(vb + c * SS + ((u ^ ((c >> 1) & 3)) * 8), &lV[(it * 256 + tid) * 8]);
    }
  };

  const int nsteps = bx * 2 + 2;
  stage(0);
  const int vkey = (p >> 1) & 3;
  for (int st = 0; st < nsteps; st++) {
    const int t0 = st * 32;
    asm volatile("s_waitcnt vmcnt(0)" ::: "memory");
    __builtin_amdgcn_s_barrier();   // tile resident in lK/lV

    // ---- QK^T (2 interleaved partial accumulators) ----
    __builtin_amdgcn_s_setprio(1);
    f32x4 sca[2], scb[2];
    sca[0] = fz; sca[1] = fz; scb[0] = fz; scb[1] = fz;
#pragma unroll
    for (int kc = 0; kc < 18; kc += 2) {
#pragma unroll
      for (int n = 0; n < 2; n++) {
        int trow = n * 16 + p;
        bf16x8 bf0 = *(const bf16x8*)&lK[trow * 576 + (((4 * kc + g) ^ (trow & 7))) * 8];
        bf16x8 bf1 = *(const bf16x8*)&lK[trow * 576 + (((4 * (kc + 1) + g) ^ (trow & 7))) * 8];
        sca[n] = mfma16(qreg[kc], bf0, sca[n]);
        scb[n] = mfma16(qreg[kc + 1], bf1, scb[n]);
      }
    }
    __builtin_amdgcn_s_setprio(0);
    f32x4 sc[2];
#pragma unroll
    for (int n = 0; n < 2; n++)
#pragma unroll
      for (int r = 0; r < 4; r++) sc[n][r] = sca[n][r] + scb[n][r];
    if (t0 + 31 > qw) {
#pragma unroll
      for (int n = 0; n < 2; n++) {
        int t = t0 + n * 16 + p;
#pragma unroll
        for (int r = 0; r < 4; r++) {
          int q = qw + g * 4 + r;
          if (t > q) sc[n][r] = -1e9f;
        }
      }
    }

    // ---- softmax max + P store (defer-max T13, THR=8); row-sum via MFMA ----
    float es[4];
    int needAny = 0;
#pragma unroll
    for (int r = 0; r < 4; r++) {
      float mx = fmaxf(sc[0][r], sc[1][r]);
#pragma unroll
      for (int mk = 1; mk < 16; mk <<= 1) mx = fmaxf(mx, __shfl_xor(mx, mk, 64));
      if (mx > mrun[r] + 8.f) { es[r] = __expf(mrun[r] - mx); mrun[r] = mx; needAny = 1; }
      else es[r] = 1.f;
      float s0 = __expf(sc[0][r] - mrun[r]);
      float s1 = __expf(sc[1][r] - mrun[r]);
      int prow = g * 4 + r;
      int swz = ((prow >> 1) & 3) * 8;
      lP[wid * 512 + prow * 32 + (p ^ swz)]        = (__bf16)s0;
      lP[wid * 512 + prow * 32 + ((16 + p) ^ swz)] = (__bf16)s1;
    }
    if (__any(needAny)) {
#pragma unroll
      for (int ct = 0; ct < 8; ct++)
#pragma unroll
        for (int r = 0; r < 4; r++) acc[ct][r] *= es[r];
    }
    bf16x8 pa = *(const bf16x8*)&lP[wid * 512 + p * 32 + ((g ^ vkey) * 8)];
    {
      f32x4 rs = mfma16(pa, ones, fz);   // row-sums of own P tile
#pragma unroll
      for (int r = 0; r < 4; r++) lrun[r] = lrun[r] * es[r] + rs[r];
    }

    // ---- PV: 16 q-rows x 128 d ----
    __builtin_amdgcn_s_setprio(1);
#pragma unroll
    for (int ct = 0; ct < 8; ct++) {
      int c = ct * 16 + p;
      bf16x8 bv = *(const bf16x8*)&lV[c * 32 + ((g ^ vkey) * 8)];
      acc[ct] = mfma16(pa, bv, acc[ct]);
    }
    __builtin_amdgcn_s_setprio(0);
    asm volatile("s_waitcnt lgkmcnt(0)" ::: "memory");
    __builtin_amdgcn_s_barrier();   // everyone done reading lK/lV
    if (st + 1 < nsteps) stage(t0 + 32);
  }

  // ---- epilogue: normalize + store to o_head[b][s][h*128+d] ----
#pragma unroll
  for (int r = 0; r < 4; r++) {
    float inv = 1.f / lrun[r];
    int64_t rb = ((int64_t)b * SS + qw + g * 4 + r) * 2048 + h * 128;
#pragma unroll
    for (int ct = 0; ct < 8; ct++) Ohead[rb + ct * 16 + p] = (__bf16)(acc[ct][r] * inv);
  }
}

extern "C" void kernel_launch(void* const* d_in, const int* in_sizes, int n_in,
                              void* d_out, int out_size, void* d_ws, size_t ws_size,
                              hipStream_t stream) {
  const float* x     = (const float*)d_in[0];
  const float* wq    = (const float*)d_in[1];
  const float* wkv_a = (const float*)d_in[2];
  const float* kvw   = (const float*)d_in[3];
  const float* wkv_b = (const float*)d_in[4];
  const float* wo    = (const float*)d_in[5];
  const float* fc    = (const float*)d_in[6];
  const float* fs    = (const float*)d_in[7];
  float* out = (float*)d_out;

  char* base = (char*)d_ws;
  const size_t OFF_KCAT  = 0;
  const size_t OFF_VT    = OFF_KCAT + 9437184ull;   // (old Vt slot; unused)
  const size_t OFF_WKVB  = OFF_VT + 8388608ull;
  const size_t OFF_WOT   = OFF_WKVB + 4194304ull;
  const size_t OFF_QCAT  = OFF_WOT + 8388608ull;
  const size_t OFF_OHEAD = OFF_QCAT + 150994944ull;
  const size_t OFF_QFULL = OFF_OHEAD + 33554432ull;
  const size_t TOTAL     = OFF_QFULL + 50331648ull;

  __bf16* Kcat    = (__bf16*)(base + OFF_KCAT);
  __bf16* wkvb_bf = (__bf16*)(base + OFF_WKVB);
  __bf16* woT     = (__bf16*)(base + OFF_WOT);
  __bf16* Qcat    = (__bf16*)(base + OFF_QCAT);
  __bf16* o_head  = (__bf16*)(base + OFF_OHEAD);
  __bf16* qfull   = (__bf16*)(base + OFF_QFULL);
  __bf16* Vt2     = (__bf16*)(base + OFF_QFULL);          // aliases qfull (dead after qpe)
  __bf16* wqT    = (__bf16*)(base + OFF_KCAT);            // dead before kvprep
  __bf16* wkvaT  = (__bf16*)(base + OFF_KCAT + 12582912); // dead before kvprep
  __bf16* xb     = (__bf16*)(base + OFF_QCAT);            // dead before q_abs
  __bf16* kvfull = (__bf16*)(base + OFF_QCAT + 33554432); // dead before q_abs
  __bf16* wbTn   = (__bf16*)(base + OFF_OHEAD);           // dead before attn

  if (ws_size < TOTAL) {
    fprintf(stderr, "kernel_launch: ws too small: need %zu have %zu\n", TOTAL, ws_size);
    return;
  }

  k_cvt<<<8192, 256, 0, stream>>>(x, xb, BB * SS * DIMM);
  k_cvt<<<1024, 256, 0, stream>>>(wkv_b, wkvb_bf, 4096 * 512);
  k_tr<<<dim3(96, 64, 1), dim3(32, 8), 0, stream>>>(wq, wqT, 2048, 3072, 0, 0);
  k_tr<<<dim3(18, 64, 1), dim3(32, 8), 0, stream>>>(wkv_a, wkvaT, 2048, 576, 0, 0);
  k_tr<<<dim3(64, 64, 1), dim3(32, 8), 0, stream>>>(wo, woT, 2048, 2048, 0, 0);
  k_tr<<<dim3(16, 4, 16), dim3(32, 8), 0, stream>>>(wkv_b, wbTn, 128, 512,
                                                    (int64_t)256 * 512, (int64_t)512 * 128);
  // qfull = xb @ wq
  k_gemm<false><<<dim3(24, 64, 1), 256, 0, stream>>>(
      xb, wqT, qfull, 3072, 2048, 2048, 2048, 3072, 0, 0, 0, 0, 0, 1, 1.0f);
  // kvfull = xb @ wkv_a
  k_gemm<false><<<dim3(5, 64, 1), 256, 0, stream>>>(
      xb, wkvaT, kvfull, 576, 2048, 2048, 2048, 576, 0, 0, 0, 0, 0, 1, 1.0f);
  k_kvprep<<<8192, 64, 0, stream>>>(kvfull, kvw, fc, fs, Kcat);
  // q_abs (batched over b,h) -> Qcat[:, :512], scaled
  k_gemm<false><<<dim3(4, 16, 64), 256, 0, stream>>>(
      qfull, wbTn, Qcat, 512, 128, 3072, 128, 576,
      (int64_t)SS * 3072, (int64_t)QKD, (int64_t)512 * 128,
      (int64_t)HH * SS * DQK, (int64_t)SS * DQK, 16, SCALE_F);
  k_qpe<<<16384, 256, 0, stream>>>(qfull, fc, fs, Qcat);
  // V_head[z][d=128][t] = w_b2[h] @ kv_c^T  (z decoded as zb=h, zh=b via Hdiv=4)
  k_gemm<false><<<dim3(16, 1, 64), 256, 0, stream>>>(
      wkvb_bf + 128 * 512, Kcat, Vt2, 2048, 512, 512, DQK, 2048,
      (int64_t)256 * 512, 0, (int64_t)SS * DQK,
      (int64_t)128 * 2048, (int64_t)16 * 128 * 2048, 4, 1.0f);
  // attention: grid (8=xcd, 256=w) -> o_head[b][s][h*128+d]
  k_attn<<<dim3(8, 256), 256, 0, stream>>>(Qcat, Kcat, Vt2, o_head);
  // out = o_head @ wo
  k_gemm<true><<<dim3(16, 64, 1), 256, 0, stream>>>(
      o_head, woT, out, 2048, 2048, 2048, 2048, 2048, 0, 0, 0, 0, 0, 1, 1.0f);
}

// Round 16
// 747.403 us; speedup vs baseline: 1.8417x; 1.0327x over previous
//
#include <hip/hip_runtime.h>
#include <hip/hip_bf16.h>
#include <cstdio>
#include <cstdint>

#define BB   4
#define SS   2048
#define DIMM 2048
#define HH   16
#define NOPED 128
#define QKD  192
#define KVR  512
#define DQK  576
#define SCALE_F 0.07216878364870323f  // 192^-0.5

typedef __attribute__((ext_vector_type(4))) float f32x4;
typedef __attribute__((ext_vector_type(8))) __bf16 bf16x8;
typedef __attribute__((ext_vector_type(8))) unsigned short u16x8;

__device__ __forceinline__ f32x4 mfma16(bf16x8 a, bf16x8 b, f32x4 c) {
  return __builtin_amdgcn_mfma_f32_16x16x32_bf16(a, b, c, 0, 0, 0);
}

// async global->LDS, 16B per lane; LDS dest must be wave-uniform base + lane*16
__device__ __forceinline__ void gl16(const __bf16* g, __bf16* l) {
  __builtin_amdgcn_global_load_lds(
      (const __attribute__((address_space(1))) unsigned int*)g,
      (__attribute__((address_space(3))) unsigned int*)l, 16, 0, 0);
}

// ---------------- f32 -> bf16 convert ----------------
__global__ void k_cvt(const float* __restrict__ in, __bf16* __restrict__ out, int n) {
  int i = (blockIdx.x * 256 + threadIdx.x) * 8;
  if (i >= n) return;
  float4 a = *(const float4*)(in + i);
  float4 b = *(const float4*)(in + i + 4);
  bf16x8 v;
  v[0] = (__bf16)a.x; v[1] = (__bf16)a.y; v[2] = (__bf16)a.z; v[3] = (__bf16)a.w;
  v[4] = (__bf16)b.x; v[5] = (__bf16)b.y; v[6] = (__bf16)b.z; v[7] = (__bf16)b.w;
  *(bf16x8*)(out + i) = v;
}

// ---------------- f32 transpose -> bf16 (batched) ----------------
__global__ void k_tr(const float* __restrict__ in, __bf16* __restrict__ out,
                     int R, int C, int64_t inBS, int64_t outBS) {
  in  += (int64_t)blockIdx.z * inBS;
  out += (int64_t)blockIdx.z * outBS;
  __shared__ float t[32][33];
  int c0 = blockIdx.x * 32, r0 = blockIdx.y * 32;
#pragma unroll
  for (int i = 0; i < 4; i++) {
    int r = r0 + threadIdx.y + i * 8, c = c0 + threadIdx.x;
    if (r < R && c < C) t[threadIdx.y + i * 8][threadIdx.x] = in[(int64_t)r * C + c];
  }
  __syncthreads();
#pragma unroll
  for (int i = 0; i < 4; i++) {
    int c = c0 + threadIdx.y + i * 8, r = r0 + threadIdx.x;
    if (c < C && r < R) out[(int64_t)c * R + r] = (__bf16)t[threadIdx.x][threadIdx.y + i * 8];
  }
}

// ---------------- generic batched MFMA GEMM (128x128, BK=32) ----------------
template <bool OUTF32>
__global__ __launch_bounds__(256) void k_gemm(
    const __bf16* __restrict__ A, const __bf16* __restrict__ Bt, void* __restrict__ Cv,
    int N, int K, int lda, int ldb, int ldc,
    int64_t aSB, int64_t aSH, int64_t bSH, int64_t cSB, int64_t cSH, int Hdiv, float scale) {
  const int z = blockIdx.z;
  const int zb = z / Hdiv, zh = z % Hdiv;
  const int64_t aBase = zb * aSB + zh * aSH;
  const int64_t bBase = zh * bSH;
  const int64_t cBase = zb * cSB + zh * cSH;
  const int n0 = blockIdx.x * 128, m0 = blockIdx.y * 128;
  const int tid = threadIdx.x, lane = tid & 63, wid = tid >> 6;
  const int p = lane & 15, g = lane >> 4;
  const int wr = (wid >> 1) * 64, wc = (wid & 1) * 64;
  __shared__ alignas(16) __bf16 lA[128 * 32];
  __shared__ alignas(16) __bf16 lB[128 * 32];
  const f32x4 fz = {};
  f32x4 acc[4][4];
#pragma unroll
  for (int i = 0; i < 4; i++)
#pragma unroll
    for (int j = 0; j < 4; j++) acc[i][j] = fz;
  const __bf16* gA0 = A + aBase + (int64_t)(m0 + (tid >> 2)) * lda + (tid & 3) * 8;
  const __bf16* gA1 = A + aBase + (int64_t)(m0 + 64 + (tid >> 2)) * lda + (tid & 3) * 8;
  const __bf16* gB0 = Bt + bBase + (int64_t)(n0 + (tid >> 2)) * ldb + (tid & 3) * 8;
  const __bf16* gB1 = Bt + bBase + (int64_t)(n0 + 64 + (tid >> 2)) * ldb + (tid & 3) * 8;
  auto stage = [&](int kt) {
    gl16(gA0 + kt, &lA[tid * 8]);
    gl16(gA1 + kt, &lA[(256 + tid) * 8]);
    gl16(gB0 + kt, &lB[tid * 8]);
    gl16(gB1 + kt, &lB[(256 + tid) * 8]);
  };
  stage(0);
  for (int kt = 0; kt < K; kt += 32) {
    asm volatile("s_waitcnt vmcnt(0)" ::: "memory");
    __builtin_amdgcn_s_barrier();
    bf16x8 af[4], bfr[4];
#pragma unroll
    for (int mi = 0; mi < 4; mi++) af[mi]  = *(const bf16x8*)&lA[(wr + mi * 16 + p) * 32 + g * 8];
#pragma unroll
    for (int ni = 0; ni < 4; ni++) bfr[ni] = *(const bf16x8*)&lB[(wc + ni * 16 + p) * 32 + g * 8];
#pragma unroll
    for (int mi = 0; mi < 4; mi++)
#pragma unroll
      for (int ni = 0; ni < 4; ni++) acc[mi][ni] = mfma16(af[mi], bfr[ni], acc[mi][ni]);
    asm volatile("s_waitcnt lgkmcnt(0)" ::: "memory");
    __builtin_amdgcn_s_barrier();
    if (kt + 32 < K) stage(kt + 32);
  }
#pragma unroll
  for (int mi = 0; mi < 4; mi++) {
#pragma unroll
    for (int ni = 0; ni < 4; ni++) {
      const int n = n0 + wc + ni * 16 + p;
      if (n < N) {
#pragma unroll
        for (int r = 0; r < 4; r++) {
          const int m = m0 + wr + mi * 16 + g * 4 + r;
          float v = acc[mi][ni][r] * scale;
          if (OUTF32) ((float*)Cv)[cBase + (int64_t)m * ldc + n] = v;
          else        ((__bf16*)Cv)[cBase + (int64_t)m * ldc + n] = (__bf16)v;
        }
      }
    }
  }
}

// ---------------- big-tile GEMM: 256x256, BK=64, 8 waves, swizzled dbuf LDS ----------------
// C = scale * A(M,K) x Bt(N,K)^T. M,N multiples of 256; K multiple of 64.
// Stage-at-top 1-ahead: tile t's loads issued at top of t-1 get a full tile
// (~2400 cy) to land -> vmcnt(0) drain ~free (fixes the m97-structure's
// exposed-latency flaw). Granule-XOR swizzle (g ^ row&7) on BOTH gl16 source
// and ds_read (rule 21; measured 0-conflict pattern in k_attn). One barrier
// per tile; per-wave lgkmcnt drains reads before it. B-frags held in regs
// across all 8 m-fragments (24 b128 reads/wave/tile).
template <bool OUTF32>
__global__ __launch_bounds__(512) void k_gemm2(
    const __bf16* __restrict__ A, const __bf16* __restrict__ Bt, void* __restrict__ Cv,
    int K, int lda, int ldb, int ldc, float scale) {
  const int n0 = blockIdx.x * 256, m0 = blockIdx.y * 256;
  const int tid = threadIdx.x, lane = tid & 63, wid = tid >> 6;
  const int p = lane & 15, g = lane >> 4;
  const int wm = wid >> 2, wn = wid & 3;   // 2(M) x 4(N) wave grid
  __shared__ alignas(16) __bf16 lA[2][256 * 64];   // 64 KB
  __shared__ alignas(16) __bf16 lB[2][256 * 64];   // 64 KB (total 128 KB)
  const f32x4 fz = {};
  f32x4 acc[8][4];
#pragma unroll
  for (int m = 0; m < 8; m++)
#pragma unroll
    for (int n = 0; n < 4; n++) acc[m][n] = fz;

  // staging: slot = it*512+tid -> row = it*64 + (tid>>3), granule = tid&7
  const int sr = tid >> 3, sg = tid & 7;
  const int scol = ((sg ^ (sr & 7)) * 8);          // source-side swizzle (involution)
  const __bf16* gA = A + (int64_t)(m0 + sr) * lda + scol;
  const __bf16* gB = Bt + (int64_t)(n0 + sr) * ldb + scol;
  auto stage = [&](int t, int buf) {
    const __bf16* a = gA + t * 64;
    const __bf16* b = gB + t * 64;
#pragma unroll
    for (int it = 0; it < 4; it++) {
      gl16(a + (int64_t)(it * 64) * lda, &lA[buf][(it * 512 + tid) * 8]);
      gl16(b + (int64_t)(it * 64) * ldb, &lB[buf][(it * 512 + tid) * 8]);
    }
  };

  const int nt = K >> 6;
  stage(0, 0);
  for (int t = 0; t < nt; t++) {
    const int cu = t & 1;
    asm volatile("s_waitcnt vmcnt(0)" ::: "memory");  // tile t resident
    __builtin_amdgcn_s_barrier();                     // all writes visible; prev buf free
    if (t + 1 < nt) stage(t + 1, cu ^ 1);             // full tile to land

    // ---- B fragments: 4n x 2kk, held across all m ----
    bf16x8 bfr[4][2];
#pragma unroll
    for (int n = 0; n < 4; n++) {
      int rb = wn * 64 + n * 16 + p;
#pragma unroll
      for (int kk = 0; kk < 2; kk++)
        bfr[n][kk] = *(const bf16x8*)&lB[cu][rb * 64 + (((kk * 4 + g) ^ (rb & 7)) * 8)];
    }
    __builtin_amdgcn_s_setprio(1);
#pragma unroll
    for (int m = 0; m < 8; m++) {
      int ra = wm * 128 + m * 16 + p;
      bf16x8 a0 = *(const bf16x8*)&lA[cu][ra * 64 + (((0 + g) ^ (ra & 7)) * 8)];
      bf16x8 a1 = *(const bf16x8*)&lA[cu][ra * 64 + (((4 + g) ^ (ra & 7)) * 8)];
#pragma unroll
      for (int n = 0; n < 4; n++) {
        acc[m][n] = mfma16(a0, bfr[n][0], acc[m][n]);
        acc[m][n] = mfma16(a1, bfr[n][1], acc[m][n]);
      }
    }
    __builtin_amdgcn_s_setprio(0);
    asm volatile("s_waitcnt lgkmcnt(0)" ::: "memory"); // own reads drained
  }

#pragma unroll
  for (int m = 0; m < 8; m++) {
#pragma unroll
    for (int n = 0; n < 4; n++) {
      const int nn = n0 + wn * 64 + n * 16 + p;
#pragma unroll
      for (int r = 0; r < 4; r++) {
        const int mm = m0 + wm * 128 + m * 16 + g * 4 + r;
        float v = acc[m][n][r] * scale;
        if (OUTF32) ((float*)Cv)[(int64_t)mm * ldc + nn] = v;
        else        ((__bf16*)Cv)[(int64_t)mm * ldc + nn] = (__bf16)v;
      }
    }
  }
}

// ---------------- kv prep: rms-norm -> Kcat[:,:512]; rope -> Kcat[:,512:576] ----------------
__global__ __launch_bounds__(64) void k_kvprep(
    const __bf16* __restrict__ kvfull, const float* __restrict__ wnorm,
    const float* __restrict__ fc, const float* __restrict__ fs,
    __bf16* __restrict__ Kcat) {
  const int row = blockIdx.x;
  const int lane = threadIdx.x;
  const int s = row & 2047;
  const __bf16* src = kvfull + (int64_t)row * DQK;
  bf16x8 v = *(const bf16x8*)(src + lane * 8);
  float f[8], ss = 0.f;
#pragma unroll
  for (int j = 0; j < 8; j++) { f[j] = (float)v[j]; ss += f[j] * f[j]; }
#pragma unroll
  for (int mk = 1; mk < 64; mk <<= 1) ss += __shfl_xor(ss, mk, 64);
  float rn = rsqrtf(ss * (1.f / 512.f) + 1e-6f);
  bf16x8 o;
#pragma unroll
  for (int j = 0; j < 8; j++) o[j] = (__bf16)(f[j] * rn * wnorm[lane * 8 + j]);
  *(bf16x8*)(Kcat + (int64_t)row * DQK + lane * 8) = o;
  if (lane < 32) {
    float xr = (float)src[512 + 2 * lane];
    float xi = (float)src[512 + 2 * lane + 1];
    float c = fc[s * 32 + lane], sn = fs[s * 32 + lane];
    Kcat[(int64_t)row * DQK + 512 + 2 * lane]     = (__bf16)(xr * c - xi * sn);
    Kcat[(int64_t)row * DQK + 512 + 2 * lane + 1] = (__bf16)(xr * sn + xi * c);
  }
}

// ---------------- q rope ----------------
__global__ void k_qpe(const __bf16* __restrict__ qfull, const float* __restrict__ fc,
                      const float* __restrict__ fs, __bf16* __restrict__ Qcat) {
  int idx = blockIdx.x * 256 + threadIdx.x;
  if (idx >= BB * HH * SS * 32) return;
  int i = idx & 31, s = (idx >> 5) & 2047, h = (idx >> 16) & 15, b = idx >> 20;
  const __bf16* src = qfull + ((int64_t)(b * SS + s)) * 3072 + h * QKD + NOPED;
  float xr = (float)src[2 * i], xi = (float)src[2 * i + 1];
  float c = fc[s * 32 + i], sn = fs[s * 32 + i];
  __bf16* dst = Qcat + (((int64_t)(b * HH + h)) * SS + s) * DQK + 512;
  dst[2 * i]     = (__bf16)((xr * c - xi * sn) * SCALE_F);
  dst[2 * i + 1] = (__bf16)((xr * sn + xi * c) * SCALE_F);
}

// ---------------- flash attention (v13/v15 proven config, 256,2) ----------------
__global__ __launch_bounds__(256, 2) void k_attn(
    const __bf16* __restrict__ Qcat, const __bf16* __restrict__ Kcat,
    const __bf16* __restrict__ Vt2, __bf16* __restrict__ Ohead) {
  const int gx = blockIdx.x;            // XCD selector
  const int w  = blockIdx.y;
  const int z  = gx * 8 + (w & 7);      // (b,h): b = z>>4
  const int yv = w >> 3;                // depth slot 0..31
  const int kk = yv >> 2, cc = yv & 3;
  const int bx = (kk & 1) ? (31 - ((kk - 1) << 1) - cc) : ((kk << 1) + cc);
  const int b = z >> 4, h = z & 15;
  const int q0 = bx * 64;
  const int tid = threadIdx.x, lane = tid & 63, wid = tid >> 6;
  const int p = lane & 15, g = lane >> 4;
  const int qw = q0 + wid * 16;
  __shared__ alignas(16) __bf16 lK[32 * 576];   // 36864 B
  __shared__ alignas(16) __bf16 lV[128 * 32];   //  8192 B
  __shared__ alignas(16) __bf16 lP[4 * 512];    //  4096 B  (total 49152)

  bf16x8 qreg[18];
  {
    const __bf16* qb = Qcat + ((int64_t)z * SS + qw + p) * DQK + g * 8;
#pragma unroll
    for (int kc = 0; kc < 18; kc++) qreg[kc] = *(const bf16x8*)(qb + kc * 32);
  }
  bf16x8 ones;
#pragma unroll
  for (int j = 0; j < 8; j++) ones[j] = (__bf16)1.0f;
  const f32x4 fz = {};
  f32x4 acc[8];
#pragma unroll
  for (int ct = 0; ct < 8; ct++) acc[ct] = fz;
  float mrun[4] = {-1e30f, -1e30f, -1e30f, -1e30f};
  float lrun[4] = {0.f, 0.f, 0.f, 0.f};

  const __bf16* kBase = Kcat + (int64_t)b * SS * DQK;
  const __bf16* vBase = Vt2 + (int64_t)z * 128 * SS;

  auto stage = [&](int t0) {
    const __bf16* kb = kBase + (int64_t)t0 * DQK;
#pragma unroll
    for (int it = 0; it < 9; it++) {
      int slot = it * 256 + tid;
      int row = slot / 72, u = slot - row * 72;
      gl16(kb + row * DQK + ((u ^ (row & 7)) * 8), &lK[(it * 256 + tid) * 8]);
    }
    const __bf16* vb = vBase + t0;
#pragma unroll
    for (int it = 0; it < 2; it++) {
      int slot = it * 256 + tid;
      int c = slot >> 2, u = slot & 3;
      gl16(vb + c * SS + ((u ^ ((c >> 1) & 3)) * 8), &lV[(it * 256 + tid) * 8]);
    }
  };

  const int nsteps = bx * 2 + 2;
  stage(0);
  const int vkey = (p >> 1) & 3;
  for (int st = 0; st < nsteps; st++) {
    const int t0 = st * 32;
    asm volatile("s_waitcnt vmcnt(0)" ::: "memory");
    __builtin_amdgcn_s_barrier();

    __builtin_amdgcn_s_setprio(1);
    f32x4 sca[2], scb[2];
    sca[0] = fz; sca[1] = fz; scb[0] = fz; scb[1] = fz;
#pragma unroll
    for (int kc = 0; kc < 18; kc += 2) {
#pragma unroll
      for (int n = 0; n < 2; n++) {
        int trow = n * 16 + p;
        bf16x8 bf0 = *(const bf16x8*)&lK[trow * 576 + (((4 * kc + g) ^ (trow & 7))) * 8];
        bf16x8 bf1 = *(const bf16x8*)&lK[trow * 576 + (((4 * (kc + 1) + g) ^ (trow & 7))) * 8];
        sca[n] = mfma16(qreg[kc], bf0, sca[n]);
        scb[n] = mfma16(qreg[kc + 1], bf1, scb[n]);
      }
    }
    __builtin_amdgcn_s_setprio(0);
    f32x4 sc[2];
#pragma unroll
    for (int n = 0; n < 2; n++)
#pragma unroll
      for (int r = 0; r < 4; r++) sc[n][r] = sca[n][r] + scb[n][r];
    if (t0 + 31 > qw) {
#pragma unroll
      for (int n = 0; n < 2; n++) {
        int t = t0 + n * 16 + p;
#pragma unroll
        for (int r = 0; r < 4; r++) {
          int q = qw + g * 4 + r;
          if (t > q) sc[n][r] = -1e9f;
        }
      }
    }

    float es[4];
    int needAny = 0;
#pragma unroll
    for (int r = 0; r < 4; r++) {
      float mx = fmaxf(sc[0][r], sc[1][r]);
#pragma unroll
      for (int mk = 1; mk < 16; mk <<= 1) mx = fmaxf(mx, __shfl_xor(mx, mk, 64));
      if (mx > mrun[r] + 8.f) { es[r] = __expf(mrun[r] - mx); mrun[r] = mx; needAny = 1; }
      else es[r] = 1.f;
      float s0 = __expf(sc[0][r] - mrun[r]);
      float s1 = __expf(sc[1][r] - mrun[r]);
      int prow = g * 4 + r;
      int swz = ((prow >> 1) & 3) * 8;
      lP[wid * 512 + prow * 32 + (p ^ swz)]        = (__bf16)s0;
      lP[wid * 512 + prow * 32 + ((16 + p) ^ swz)] = (__bf16)s1;
    }
    if (__any(needAny)) {
#pragma unroll
      for (int ct = 0; ct < 8; ct++)
#pragma unroll
        for (int r = 0; r < 4; r++) acc[ct][r] *= es[r];
    }
    bf16x8 pa = *(const bf16x8*)&lP[wid * 512 + p * 32 + ((g ^ vkey) * 8)];
    {
      f32x4 rs = mfma16(pa, ones, fz);
#pragma unroll
      for (int r = 0; r < 4; r++) lrun[r] = lrun[r] * es[r] + rs[r];
    }

    __builtin_amdgcn_s_setprio(1);
#pragma unroll
    for (int ct = 0; ct < 8; ct++) {
      int c = ct * 16 + p;
      bf16x8 bv = *(const bf16x8*)&lV[c * 32 + ((g ^ vkey) * 8)];
      acc[ct] = mfma16(pa, bv, acc[ct]);
    }
    __builtin_amdgcn_s_setprio(0);
    asm volatile("s_waitcnt lgkmcnt(0)" ::: "memory");
    __builtin_amdgcn_s_barrier();
    if (st + 1 < nsteps) stage(t0 + 32);
  }

#pragma unroll
  for (int r = 0; r < 4; r++) {
    float inv = 1.f / lrun[r];
    int64_t rb = ((int64_t)b * SS + qw + g * 4 + r) * 2048 + h * 128;
#pragma unroll
    for (int ct = 0; ct < 8; ct++) Ohead[rb + ct * 16 + p] = (__bf16)(acc[ct][r] * inv);
  }
}

extern "C" void kernel_launch(void* const* d_in, const int* in_sizes, int n_in,
                              void* d_out, int out_size, void* d_ws, size_t ws_size,
                              hipStream_t stream) {
  const float* x     = (const float*)d_in[0];
  const float* wq    = (const float*)d_in[1];
  const float* wkv_a = (const float*)d_in[2];
  const float* kvw   = (const float*)d_in[3];
  const float* wkv_b = (const float*)d_in[4];
  const float* wo    = (const float*)d_in[5];
  const float* fc    = (const float*)d_in[6];
  const float* fs    = (const float*)d_in[7];
  float* out = (float*)d_out;

  char* base = (char*)d_ws;
  const size_t OFF_KCAT  = 0;
  const size_t OFF_VT    = OFF_KCAT + 9437184ull;   // (old Vt slot; unused)
  const size_t OFF_WKVB  = OFF_VT + 8388608ull;
  const size_t OFF_WOT   = OFF_WKVB + 4194304ull;
  const size_t OFF_QCAT  = OFF_WOT + 8388608ull;
  const size_t OFF_OHEAD = OFF_QCAT + 150994944ull;
  const size_t OFF_QFULL = OFF_OHEAD + 33554432ull;
  const size_t TOTAL     = OFF_QFULL + 50331648ull;

  __bf16* Kcat    = (__bf16*)(base + OFF_KCAT);
  __bf16* wkvb_bf = (__bf16*)(base + OFF_WKVB);
  __bf16* woT     = (__bf16*)(base + OFF_WOT);
  __bf16* Qcat    = (__bf16*)(base + OFF_QCAT);
  __bf16* o_head  = (__bf16*)(base + OFF_OHEAD);
  __bf16* qfull   = (__bf16*)(base + OFF_QFULL);
  __bf16* Vt2     = (__bf16*)(base + OFF_QFULL);          // aliases qfull (dead after qpe)
  __bf16* wqT    = (__bf16*)(base + OFF_KCAT);            // dead before kvprep
  __bf16* wkvaT  = (__bf16*)(base + OFF_KCAT + 12582912); // dead before kvprep
  __bf16* xb     = (__bf16*)(base + OFF_QCAT);            // dead before q_abs
  __bf16* kvfull = (__bf16*)(base + OFF_QCAT + 33554432); // dead before q_abs
  __bf16* wbTn   = (__bf16*)(base + OFF_OHEAD);           // dead before attn

  if (ws_size < TOTAL) {
    fprintf(stderr, "kernel_launch: ws too small: need %zu have %zu\n", TOTAL, ws_size);
    return;
  }

  k_cvt<<<8192, 256, 0, stream>>>(x, xb, BB * SS * DIMM);
  k_cvt<<<1024, 256, 0, stream>>>(wkv_b, wkvb_bf, 4096 * 512);
  k_tr<<<dim3(96, 64, 1), dim3(32, 8), 0, stream>>>(wq, wqT, 2048, 3072, 0, 0);
  k_tr<<<dim3(18, 64, 1), dim3(32, 8), 0, stream>>>(wkv_a, wkvaT, 2048, 576, 0, 0);
  k_tr<<<dim3(64, 64, 1), dim3(32, 8), 0, stream>>>(wo, woT, 2048, 2048, 0, 0);
  k_tr<<<dim3(16, 4, 16), dim3(32, 8), 0, stream>>>(wkv_b, wbTn, 128, 512,
                                                    (int64_t)256 * 512, (int64_t)512 * 128);
  // qfull = xb @ wq  (256x256 big-tile kernel)
  k_gemm2<false><<<dim3(12, 32), 512, 0, stream>>>(
      xb, wqT, qfull, 2048, 2048, 2048, 3072, 1.0f);
  // kvfull = xb @ wkv_a
  k_gemm<false><<<dim3(5, 64, 1), 256, 0, stream>>>(
      xb, wkvaT, kvfull, 576, 2048, 2048, 2048, 576, 0, 0, 0, 0, 0, 1, 1.0f);
  k_kvprep<<<8192, 64, 0, stream>>>(kvfull, kvw, fc, fs, Kcat);
  // q_abs (batched over b,h) -> Qcat[:, :512], scaled
  k_gemm<false><<<dim3(4, 16, 64), 256, 0, stream>>>(
      qfull, wbTn, Qcat, 512, 128, 3072, 128, 576,
      (int64_t)SS * 3072, (int64_t)QKD, (int64_t)512 * 128,
      (int64_t)HH * SS * DQK, (int64_t)SS * DQK, 16, SCALE_F);
  k_qpe<<<16384, 256, 0, stream>>>(qfull, fc, fs, Qcat);
  // V_head[z][d=128][t] = w_b2[h] @ kv_c^T
  k_gemm<false><<<dim3(16, 1, 64), 256, 0, stream>>>(
      wkvb_bf + 128 * 512, Kcat, Vt2, 2048, 512, 512, DQK, 2048,
      (int64_t)256 * 512, 0, (int64_t)SS * DQK,
      (int64_t)128 * 2048, (int64_t)16 * 128 * 2048, 4, 1.0f);
  // attention: grid (8=xcd, 256=w) -> o_head[b][s][h*128+d]
  k_attn<<<dim3(8, 256), 256, 0, stream>>>(Qcat, Kcat, Vt2, o_head);
  // out = o_head @ wo  (256x256 big-tile kernel, f32 out)
  k_gemm2<true><<<dim3(8, 32), 512, 0, stream>>>(
      o_head, woT, out, 2048, 2048, 2048, 2048, 1.0f);
}